// Round 1
// baseline (860.886 us; speedup 1.0000x reference)
//
#include <hip/hip_runtime.h>

#define N_   512
#define V_   3889
#define V3   11667      // V_*3
#define J_   35
#define NB_  20
#define PF_K 306        // 34*9

__constant__ int c_parents[J_] = {0,0,1,2,3,4,5,6,7,8,9,6,11,12,13,6,15,16,17,18,
                                  16,20,21,22,23,16,25,26,27,28,29,30,16,1,1};

// ---------------- v_shaped = v_template + deform + beta @ shapedirs ----------
#define VS_G 4
__global__ __launch_bounds__(256) void k_vshaped(
    const float* __restrict__ beta, const float* __restrict__ deform,
    const float* __restrict__ vt,   const float* __restrict__ sd,
    float* __restrict__ VS) {
  int e  = blockIdx.x * 256 + threadIdx.x;   // element within a row (v*3+c)
  int n0 = blockIdx.y * VS_G;
  if (e >= V3) return;
  float base = vt[e];
  float acc[VS_G];
#pragma unroll
  for (int i = 0; i < VS_G; ++i) acc[i] = base + deform[(size_t)(n0 + i) * V3 + e];
#pragma unroll
  for (int b = 0; b < NB_; ++b) {
    float sv = sd[(size_t)b * V3 + e];
#pragma unroll
    for (int i = 0; i < VS_G; ++i) acc[i] += beta[(n0 + i) * NB_ + b] * sv;  // uniform -> s_load
  }
#pragma unroll
  for (int i = 0; i < VS_G; ++i) VS[(size_t)(n0 + i) * V3 + e] = acc[i];
}

// ---------------- Rodrigues: Rs (output) + pose_feature --------------------
__global__ void k_rod(const float* __restrict__ theta,
                      float* __restrict__ Rs_out, float* __restrict__ pf) {
  int i = blockIdx.x * blockDim.x + threadIdx.x;
  if (i >= N_ * J_) return;
  int n = i / J_, j = i % J_;
  const float* th = theta + n * (J_ * 3) + j * 3;
  float t0 = th[0], t1 = th[1], t2 = th[2];
  float angle = sqrtf(t0 * t0 + t1 * t1 + t2 * t2 + 1e-8f);
  float inv = 1.0f / angle;
  float r0 = t0 * inv, r1 = t1 * inv, r2 = t2 * inv;
  float s, c;
  sincosf(angle, &s, &c);
  float omc = 1.0f - c;
  float R[9];
  R[0] = c + omc * r0 * r0;      R[1] = omc * r0 * r1 - s * r2;  R[2] = omc * r0 * r2 + s * r1;
  R[3] = omc * r1 * r0 + s * r2; R[4] = c + omc * r1 * r1;       R[5] = omc * r1 * r2 - s * r0;
  R[6] = omc * r2 * r0 - s * r1; R[7] = omc * r2 * r1 + s * r0;  R[8] = c + omc * r2 * r2;
  float* ro = Rs_out + (size_t)n * (J_ * 9) + j * 9;
#pragma unroll
  for (int k = 0; k < 9; ++k) ro[k] = R[k];
  if (j > 0) {
    float* p = pf + (size_t)n * PF_K + (j - 1) * 9;
#pragma unroll
    for (int k = 0; k < 9; ++k)
      p[k] = R[k] - ((k == 0 || k == 4 || k == 8) ? 1.0f : 0.0f);
  }
}

// --------- dst[n,j,c] = sum_v src[n,v,c] * Jr[v,j]   (split-K + atomics) ----
#define JR_CHUNK 1024
__global__ void k_jreduce(const float* __restrict__ src, const float* __restrict__ Jr,
                          float* __restrict__ dst) {
  int n = blockIdx.x;
  int v0 = blockIdx.y * JR_CHUNK;
  int t = threadIdx.x;          // 128 threads, 105 active
  if (t >= J_ * 3) return;
  int j = t / 3, c = t % 3;
  int vend = min(V_, v0 + JR_CHUNK);
  const float* s = src + (size_t)n * V3 + c;
  float acc = 0.f;
  for (int v = v0; v < vend; ++v)
    acc += Jr[v * J_ + j] * s[3 * v];
  atomicAdd(dst + n * (J_ * 3) + t, acc);
}

// ---------------- kinematic chain -> A[n][j][3][4] --------------------------
__global__ __launch_bounds__(256) void k_chain(
    const float* __restrict__ Rs, const float* __restrict__ Jp,
    const float* __restrict__ se, float* __restrict__ Aout) {
  __shared__ float loc[4][J_][12];
  __shared__ float res[4][J_][12];
  int t = threadIdx.x;
  int w = t >> 6, l = t & 63;
  int n = blockIdx.x * 4 + w;

  if (l < J_) {
    int j = l;
    const float* R = Rs + (size_t)n * (J_ * 9) + j * 9;
    float r[9];
#pragma unroll
    for (int k = 0; k < 9; ++k) r[k] = R[k];
    if (j == 0) {
#pragma unroll
      for (int rr = 0; rr < 3; ++rr) {
        loc[w][0][rr * 4 + 0] = r[rr * 3 + 0];
        loc[w][0][rr * 4 + 1] = r[rr * 3 + 1];
        loc[w][0][rr * 4 + 2] = r[rr * 3 + 2];
        loc[w][0][rr * 4 + 3] = Jp[n * 105 + rr];
      }
#pragma unroll
      for (int k = 0; k < 12; ++k) res[w][0][k] = loc[w][0][k];
    } else {
      int p = c_parents[j];
      float si[3], sp[3], jh[3];
#pragma unroll
      for (int cidx = 0; cidx < 3; ++cidx) {
        si[cidx] = se[n * 105 + j * 3 + cidx];
        sp[cidx] = se[n * 105 + p * 3 + cidx];
        jh[cidx] = Jp[n * 105 + j * 3 + cidx] - Jp[n * 105 + p * 3 + cidx];
      }
#pragma unroll
      for (int rr = 0; rr < 3; ++rr) {
        float invp = 1.0f / sp[rr];
        loc[w][j][rr * 4 + 0] = r[rr * 3 + 0] * si[0] * invp;
        loc[w][j][rr * 4 + 1] = r[rr * 3 + 1] * si[1] * invp;
        loc[w][j][rr * 4 + 2] = r[rr * 3 + 2] * si[2] * invp;
        loc[w][j][rr * 4 + 3] = jh[rr];
      }
    }
  }
  __syncthreads();

  for (int i = 1; i < J_; ++i) {
    if (l < 12) {
      int p = c_parents[i];
      int rr = l >> 2, cc = l & 3;
      float acc = (cc == 3) ? res[w][p][rr * 4 + 3] : 0.f;
#pragma unroll
      for (int k = 0; k < 3; ++k)
        acc += res[w][p][rr * 4 + k] * loc[w][i][k * 4 + cc];
      res[w][i][l] = acc;
    }
    __syncthreads();
  }

  if (l < J_) {
    int j = l;
    float jx = Jp[n * 105 + j * 3 + 0];
    float jy = Jp[n * 105 + j * 3 + 1];
    float jz = Jp[n * 105 + j * 3 + 2];
    float* Ao = Aout + (size_t)n * (J_ * 12) + j * 12;
#pragma unroll
    for (int rr = 0; rr < 3; ++rr) {
      float a0 = res[w][j][rr * 4 + 0];
      float a1 = res[w][j][rr * 4 + 1];
      float a2 = res[w][j][rr * 4 + 2];
      float a3 = res[w][j][rr * 4 + 3];
      Ao[rr * 4 + 0] = a0;
      Ao[rr * 4 + 1] = a1;
      Ao[rr * 4 + 2] = a2;
      Ao[rr * 4 + 3] = a3 - (a0 * jx + a1 * jy + a2 * jz);
    }
  }
}

// ---------------- v_posed = v_shaped + pose_feature @ posedirs (in place) ---
#define VP_G 16
__global__ __launch_bounds__(256) void k_vposed(
    const float* __restrict__ pf, const float* __restrict__ pd,
    float* __restrict__ VS) {
  int e = blockIdx.x * 256 + threadIdx.x;
  if (e >= V3) return;
  int n0 = blockIdx.y * VP_G;
  float acc[VP_G];
#pragma unroll
  for (int i = 0; i < VP_G; ++i) acc[i] = VS[(size_t)(n0 + i) * V3 + e];
  const float* pfb = pf + (size_t)n0 * PF_K;
  for (int k = 0; k < PF_K; ++k) {
    float pdv = pd[(size_t)k * V3 + e];
#pragma unroll
    for (int i = 0; i < VP_G; ++i)
      acc[i] += pfb[i * PF_K + k] * pdv;     // uniform -> s_load broadcast
  }
#pragma unroll
  for (int i = 0; i < VP_G; ++i) VS[(size_t)(n0 + i) * V3 + e] = acc[i];
}

// ---------------- skinning: verts = (sum_j w*A) @ [v_posed,1] + trans -------
__global__ __launch_bounds__(256) void k_skin(
    const float* __restrict__ Aw, const float* __restrict__ wts,
    const float* __restrict__ trans, float* __restrict__ VT) {
  __shared__ float A_s[J_ * 12];
  __shared__ float w_s[256 * J_];
  int n = blockIdx.y;
  int v0 = blockIdx.x * 256;
  int t = threadIdx.x;
  for (int i = t; i < J_ * 12; i += 256) A_s[i] = Aw[(size_t)n * (J_ * 12) + i];
  int nv = min(256, V_ - v0);
  for (int i = t; i < nv * J_; i += 256) w_s[i] = wts[(size_t)v0 * J_ + i];
  __syncthreads();
  int v = v0 + t;
  if (v < V_) {
    float T[12];
#pragma unroll
    for (int k = 0; k < 12; ++k) T[k] = 0.f;
#pragma unroll
    for (int j = 0; j < J_; ++j) {
      float wj = w_s[t * J_ + j];
#pragma unroll
      for (int k = 0; k < 12; ++k) T[k] += wj * A_s[j * 12 + k];
    }
    float* p = VT + (size_t)n * V3 + 3 * v;
    float x = p[0], y = p[1], z = p[2];
    float tx = trans[n * 3 + 0], ty = trans[n * 3 + 1], tz = trans[n * 3 + 2];
    p[0] = T[0] * x + T[1] * y + T[2]  * z + T[3]  + tx;
    p[1] = T[4] * x + T[5] * y + T[6]  * z + T[7]  + ty;
    p[2] = T[8] * x + T[9] * y + T[10] * z + T[11] + tz;
  }
}

extern "C" void kernel_launch(void* const* d_in, const int* in_sizes, int n_in,
                              void* d_out, int out_size, void* d_ws, size_t ws_size,
                              hipStream_t stream) {
  const float* beta   = (const float*)d_in[0];
  const float* theta  = (const float*)d_in[1];
  const float* se     = (const float*)d_in[2];   // betas_extra (scales)
  const float* deform = (const float*)d_in[3];
  const float* trans  = (const float*)d_in[4];
  const float* vt     = (const float*)d_in[5];
  const float* sd     = (const float*)d_in[6];
  const float* pd     = (const float*)d_in[7];
  const float* Jr     = (const float*)d_in[8];
  const float* wts    = (const float*)d_in[9];

  float* out    = (float*)d_out;
  float* verts  = out;                               // N*V3 (also v_shaped/v_posed buffer)
  float* joints = out + (size_t)N_ * V3;             // N*105
  float* Rs     = joints + (size_t)N_ * 105;         // N*315

  float* ws = (float*)d_ws;
  float* pf = ws;                                    // N*306
  float* Jp = pf + (size_t)N_ * PF_K;                // N*105
  float* Aw = Jp + (size_t)N_ * 105;                 // N*420

  hipMemsetAsync(Jp, 0, (size_t)N_ * 105 * sizeof(float), stream);
  hipMemsetAsync(joints, 0, (size_t)N_ * 105 * sizeof(float), stream);

  k_vshaped<<<dim3(46, N_ / VS_G), 256, 0, stream>>>(beta, deform, vt, sd, verts);
  k_rod<<<(N_ * J_ + 63) / 64, 64, 0, stream>>>(theta, Rs, pf);
  k_jreduce<<<dim3(N_, 4), 128, 0, stream>>>(verts, Jr, Jp);
  k_chain<<<N_ / 4, 256, 0, stream>>>(Rs, Jp, se, Aw);
  k_vposed<<<dim3(46, N_ / VP_G), 256, 0, stream>>>(pf, pd, verts);
  k_skin<<<dim3(16, N_), 256, 0, stream>>>(Aw, wts, trans, verts);
  k_jreduce<<<dim3(N_, 4), 128, 0, stream>>>(verts, Jr, joints);
}

// Round 2
// 400.353 us; speedup vs baseline: 2.1503x; 2.1503x over previous
//
#include <hip/hip_runtime.h>

#define N_   512
#define V_   3889
#define V3   11667      // V_*3
#define J_   35
#define NB_  20
#define PF_K 306        // 34*9

__constant__ int c_parents[J_] = {0,0,1,2,3,4,5,6,7,8,9,6,11,12,13,6,15,16,17,18,
                                  16,20,21,22,23,16,25,26,27,28,29,30,16,1,1};

// ---------------- v_shaped = v_template + deform + beta @ shapedirs ----------
#define VS_G 4
__global__ __launch_bounds__(256) void k_vshaped(
    const float* __restrict__ beta, const float* __restrict__ deform,
    const float* __restrict__ vt,   const float* __restrict__ sd,
    float* __restrict__ VS) {
  int e  = blockIdx.x * 256 + threadIdx.x;   // element within a row (v*3+c)
  int n0 = blockIdx.y * VS_G;
  if (e >= V3) return;
  float base = vt[e];
  float acc[VS_G];
#pragma unroll
  for (int i = 0; i < VS_G; ++i) acc[i] = base + deform[(size_t)(n0 + i) * V3 + e];
#pragma unroll
  for (int b = 0; b < NB_; ++b) {
    float sv = sd[(size_t)b * V3 + e];
#pragma unroll
    for (int i = 0; i < VS_G; ++i) acc[i] += beta[(n0 + i) * NB_ + b] * sv;  // uniform -> s_load
  }
#pragma unroll
  for (int i = 0; i < VS_G; ++i) VS[(size_t)(n0 + i) * V3 + e] = acc[i];
}

// ---------------- Rodrigues: Rs (output) + pose_feature --------------------
__global__ void k_rod(const float* __restrict__ theta,
                      float* __restrict__ Rs_out, float* __restrict__ pf) {
  int i = blockIdx.x * blockDim.x + threadIdx.x;
  if (i >= N_ * J_) return;
  int n = i / J_, j = i % J_;
  const float* th = theta + n * (J_ * 3) + j * 3;
  float t0 = th[0], t1 = th[1], t2 = th[2];
  float angle = sqrtf(t0 * t0 + t1 * t1 + t2 * t2 + 1e-8f);
  float inv = 1.0f / angle;
  float r0 = t0 * inv, r1 = t1 * inv, r2 = t2 * inv;
  float s, c;
  sincosf(angle, &s, &c);
  float omc = 1.0f - c;
  float R[9];
  R[0] = c + omc * r0 * r0;      R[1] = omc * r0 * r1 - s * r2;  R[2] = omc * r0 * r2 + s * r1;
  R[3] = omc * r1 * r0 + s * r2; R[4] = c + omc * r1 * r1;       R[5] = omc * r1 * r2 - s * r0;
  R[6] = omc * r2 * r0 - s * r1; R[7] = omc * r2 * r1 + s * r0;  R[8] = c + omc * r2 * r2;
  float* ro = Rs_out + (size_t)n * (J_ * 9) + j * 9;
#pragma unroll
  for (int k = 0; k < 9; ++k) ro[k] = R[k];
  if (j > 0) {
    float* p = pf + (size_t)n * PF_K + (j - 1) * 9;
#pragma unroll
    for (int k = 0; k < 9; ++k)
      p[k] = R[k] - ((k == 0 || k == 4 || k == 8) ? 1.0f : 0.0f);
  }
}

// ---------------- transpose Jr[V][J] -> JrT[J][V] ---------------------------
__global__ __launch_bounds__(256) void k_trans_jr(
    const float* __restrict__ Jr, float* __restrict__ JrT) {
  int idx = blockIdx.x * 256 + threadIdx.x;     // flat over JrT (coalesced writes)
  if (idx >= V_ * J_) return;
  int j = idx / V_, v = idx % V_;
  JrT[idx] = Jr[v * J_ + j];
}

// --------- dst[n,j,c] = sum_v src[n,v,c] * JrT[j,v] -------------------------
// one wave owns (JRED_NG n's x JRED_JG j's); lanes stride v (coalesced)
#define JRED_NG 2
#define JRED_JG 5
#define JRED_WAVES ((N_ / JRED_NG) * (J_ / JRED_JG))   // 256*7 = 1792
__global__ __launch_bounds__(256) void k_jreduce2(
    const float* __restrict__ src, const float* __restrict__ JrT,
    float* __restrict__ dst) {
  int t = threadIdx.x;
  int lane = t & 63;
  int w = blockIdx.x * 4 + (t >> 6);
  int npair = w / (J_ / JRED_JG);
  int jg    = w % (J_ / JRED_JG);
  int n0 = npair * JRED_NG;
  int j0 = jg * JRED_JG;
  const float* s0 = src + (size_t)n0 * V3;

  float acc[JRED_NG][JRED_JG][3];
#pragma unroll
  for (int nn = 0; nn < JRED_NG; ++nn)
#pragma unroll
    for (int jj = 0; jj < JRED_JG; ++jj)
#pragma unroll
      for (int cc = 0; cc < 3; ++cc) acc[nn][jj][cc] = 0.f;

  for (int iv = 0; iv < (V_ + 63) / 64; ++iv) {
    int v = iv * 64 + lane;
    bool ok = v < V_;
    float jr[JRED_JG];
#pragma unroll
    for (int jj = 0; jj < JRED_JG; ++jj)
      jr[jj] = ok ? JrT[(size_t)(j0 + jj) * V_ + v] : 0.f;
#pragma unroll
    for (int nn = 0; nn < JRED_NG; ++nn) {
      float sx = ok ? s0[(size_t)nn * V3 + 3 * v + 0] : 0.f;
      float sy = ok ? s0[(size_t)nn * V3 + 3 * v + 1] : 0.f;
      float sz = ok ? s0[(size_t)nn * V3 + 3 * v + 2] : 0.f;
#pragma unroll
      for (int jj = 0; jj < JRED_JG; ++jj) {
        acc[nn][jj][0] += jr[jj] * sx;
        acc[nn][jj][1] += jr[jj] * sy;
        acc[nn][jj][2] += jr[jj] * sz;
      }
    }
  }

  // cross-lane reduce (64 lanes)
#pragma unroll
  for (int nn = 0; nn < JRED_NG; ++nn)
#pragma unroll
    for (int jj = 0; jj < JRED_JG; ++jj)
#pragma unroll
      for (int cc = 0; cc < 3; ++cc) {
        float v = acc[nn][jj][cc];
#pragma unroll
        for (int off = 32; off > 0; off >>= 1)
          v += __shfl_down(v, off, 64);
        acc[nn][jj][cc] = v;
      }

  if (lane == 0) {
#pragma unroll
    for (int nn = 0; nn < JRED_NG; ++nn)
#pragma unroll
      for (int jj = 0; jj < JRED_JG; ++jj)
#pragma unroll
        for (int cc = 0; cc < 3; ++cc)
          dst[(n0 + nn) * 105 + (j0 + jj) * 3 + cc] = acc[nn][jj][cc];
  }
}

// ---------------- kinematic chain -> A[n][j][3][4] --------------------------
__global__ __launch_bounds__(256) void k_chain(
    const float* __restrict__ Rs, const float* __restrict__ Jp,
    const float* __restrict__ se, float* __restrict__ Aout) {
  __shared__ float loc[4][J_][12];
  __shared__ float res[4][J_][12];
  int t = threadIdx.x;
  int w = t >> 6, l = t & 63;
  int n = blockIdx.x * 4 + w;

  if (l < J_) {
    int j = l;
    const float* R = Rs + (size_t)n * (J_ * 9) + j * 9;
    float r[9];
#pragma unroll
    for (int k = 0; k < 9; ++k) r[k] = R[k];
    if (j == 0) {
#pragma unroll
      for (int rr = 0; rr < 3; ++rr) {
        loc[w][0][rr * 4 + 0] = r[rr * 3 + 0];
        loc[w][0][rr * 4 + 1] = r[rr * 3 + 1];
        loc[w][0][rr * 4 + 2] = r[rr * 3 + 2];
        loc[w][0][rr * 4 + 3] = Jp[n * 105 + rr];
      }
#pragma unroll
      for (int k = 0; k < 12; ++k) res[w][0][k] = loc[w][0][k];
    } else {
      int p = c_parents[j];
      float si[3], sp[3], jh[3];
#pragma unroll
      for (int cidx = 0; cidx < 3; ++cidx) {
        si[cidx] = se[n * 105 + j * 3 + cidx];
        sp[cidx] = se[n * 105 + p * 3 + cidx];
        jh[cidx] = Jp[n * 105 + j * 3 + cidx] - Jp[n * 105 + p * 3 + cidx];
      }
#pragma unroll
      for (int rr = 0; rr < 3; ++rr) {
        float invp = 1.0f / sp[rr];
        loc[w][j][rr * 4 + 0] = r[rr * 3 + 0] * si[0] * invp;
        loc[w][j][rr * 4 + 1] = r[rr * 3 + 1] * si[1] * invp;
        loc[w][j][rr * 4 + 2] = r[rr * 3 + 2] * si[2] * invp;
        loc[w][j][rr * 4 + 3] = jh[rr];
      }
    }
  }
  __syncthreads();

  for (int i = 1; i < J_; ++i) {
    if (l < 12) {
      int p = c_parents[i];
      int rr = l >> 2, cc = l & 3;
      float acc = (cc == 3) ? res[w][p][rr * 4 + 3] : 0.f;
#pragma unroll
      for (int k = 0; k < 3; ++k)
        acc += res[w][p][rr * 4 + k] * loc[w][i][k * 4 + cc];
      res[w][i][l] = acc;
    }
    __syncthreads();
  }

  if (l < J_) {
    int j = l;
    float jx = Jp[n * 105 + j * 3 + 0];
    float jy = Jp[n * 105 + j * 3 + 1];
    float jz = Jp[n * 105 + j * 3 + 2];
    float* Ao = Aout + (size_t)n * (J_ * 12) + j * 12;
#pragma unroll
    for (int rr = 0; rr < 3; ++rr) {
      float a0 = res[w][j][rr * 4 + 0];
      float a1 = res[w][j][rr * 4 + 1];
      float a2 = res[w][j][rr * 4 + 2];
      float a3 = res[w][j][rr * 4 + 3];
      Ao[rr * 4 + 0] = a0;
      Ao[rr * 4 + 1] = a1;
      Ao[rr * 4 + 2] = a2;
      Ao[rr * 4 + 3] = a3 - (a0 * jx + a1 * jy + a2 * jz);
    }
  }
}

// ---------------- v_posed = v_shaped + pose_feature @ posedirs (in place) ---
#define VP_G 16
__global__ __launch_bounds__(256) void k_vposed(
    const float* __restrict__ pf, const float* __restrict__ pd,
    float* __restrict__ VS) {
  int e = blockIdx.x * 256 + threadIdx.x;
  if (e >= V3) return;
  int n0 = blockIdx.y * VP_G;
  float acc[VP_G];
#pragma unroll
  for (int i = 0; i < VP_G; ++i) acc[i] = VS[(size_t)(n0 + i) * V3 + e];
  const float* pfb = pf + (size_t)n0 * PF_K;
  for (int k = 0; k < PF_K; ++k) {
    float pdv = pd[(size_t)k * V3 + e];
#pragma unroll
    for (int i = 0; i < VP_G; ++i)
      acc[i] += pfb[i * PF_K + k] * pdv;     // uniform -> s_load broadcast
  }
#pragma unroll
  for (int i = 0; i < VP_G; ++i) VS[(size_t)(n0 + i) * V3 + e] = acc[i];
}

// ---------------- skinning: verts = (sum_j w*A) @ [v_posed,1] + trans -------
__global__ __launch_bounds__(256) void k_skin(
    const float* __restrict__ Aw, const float* __restrict__ wts,
    const float* __restrict__ trans, float* __restrict__ VT) {
  __shared__ float A_s[J_ * 12];
  __shared__ float w_s[256 * J_];
  int n = blockIdx.y;
  int v0 = blockIdx.x * 256;
  int t = threadIdx.x;
  for (int i = t; i < J_ * 12; i += 256) A_s[i] = Aw[(size_t)n * (J_ * 12) + i];
  int nv = min(256, V_ - v0);
  for (int i = t; i < nv * J_; i += 256) w_s[i] = wts[(size_t)v0 * J_ + i];
  __syncthreads();
  int v = v0 + t;
  if (v < V_) {
    float T[12];
#pragma unroll
    for (int k = 0; k < 12; ++k) T[k] = 0.f;
#pragma unroll
    for (int j = 0; j < J_; ++j) {
      float wj = w_s[t * J_ + j];
#pragma unroll
      for (int k = 0; k < 12; ++k) T[k] += wj * A_s[j * 12 + k];
    }
    float* p = VT + (size_t)n * V3 + 3 * v;
    float x = p[0], y = p[1], z = p[2];
    float tx = trans[n * 3 + 0], ty = trans[n * 3 + 1], tz = trans[n * 3 + 2];
    p[0] = T[0] * x + T[1] * y + T[2]  * z + T[3]  + tx;
    p[1] = T[4] * x + T[5] * y + T[6]  * z + T[7]  + ty;
    p[2] = T[8] * x + T[9] * y + T[10] * z + T[11] + tz;
  }
}

extern "C" void kernel_launch(void* const* d_in, const int* in_sizes, int n_in,
                              void* d_out, int out_size, void* d_ws, size_t ws_size,
                              hipStream_t stream) {
  const float* beta   = (const float*)d_in[0];
  const float* theta  = (const float*)d_in[1];
  const float* se     = (const float*)d_in[2];   // betas_extra (scales)
  const float* deform = (const float*)d_in[3];
  const float* trans  = (const float*)d_in[4];
  const float* vt     = (const float*)d_in[5];
  const float* sd     = (const float*)d_in[6];
  const float* pd     = (const float*)d_in[7];
  const float* Jr     = (const float*)d_in[8];
  const float* wts    = (const float*)d_in[9];

  float* out    = (float*)d_out;
  float* verts  = out;                               // N*V3 (also v_shaped/v_posed buffer)
  float* joints = out + (size_t)N_ * V3;             // N*105
  float* Rs     = joints + (size_t)N_ * 105;         // N*315

  float* ws = (float*)d_ws;
  float* pf  = ws;                                   // N*306
  float* Jp  = pf + (size_t)N_ * PF_K;               // N*105
  float* Aw  = Jp + (size_t)N_ * 105;                // N*420
  float* JrT = Aw + (size_t)N_ * 420;                // J*V = 136115

  k_vshaped<<<dim3(46, N_ / VS_G), 256, 0, stream>>>(beta, deform, vt, sd, verts);
  k_trans_jr<<<(V_ * J_ + 255) / 256, 256, 0, stream>>>(Jr, JrT);
  k_rod<<<(N_ * J_ + 63) / 64, 64, 0, stream>>>(theta, Rs, pf);
  k_jreduce2<<<JRED_WAVES / 4, 256, 0, stream>>>(verts, JrT, Jp);
  k_chain<<<N_ / 4, 256, 0, stream>>>(Rs, Jp, se, Aw);
  k_vposed<<<dim3(46, N_ / VP_G), 256, 0, stream>>>(pf, pd, verts);
  k_skin<<<dim3(16, N_), 256, 0, stream>>>(Aw, wts, trans, verts);
  k_jreduce2<<<JRED_WAVES / 4, 256, 0, stream>>>(verts, JrT, joints);
}

// Round 3
// 340.225 us; speedup vs baseline: 2.5303x; 1.1767x over previous
//
#include <hip/hip_runtime.h>

#define N_   512
#define V_   3889
#define V3   11667      // V_*3
#define J_   35
#define NB_  20
#define PF_K 306        // 34*9

__constant__ int c_parents[J_] = {0,0,1,2,3,4,5,6,7,8,9,6,11,12,13,6,15,16,17,18,
                                  16,20,21,22,23,16,25,26,27,28,29,30,16,1,1};

// ---------------- v_shaped = v_template + deform + beta @ shapedirs ----------
#define VS_G 4
__global__ __launch_bounds__(256) void k_vshaped(
    const float* __restrict__ beta, const float* __restrict__ deform,
    const float* __restrict__ vt,   const float* __restrict__ sd,
    float* __restrict__ VS) {
  int e  = blockIdx.x * 256 + threadIdx.x;   // element within a row (v*3+c)
  int n0 = blockIdx.y * VS_G;
  if (e >= V3) return;
  float base = vt[e];
  float acc[VS_G];
#pragma unroll
  for (int i = 0; i < VS_G; ++i) acc[i] = base + deform[(size_t)(n0 + i) * V3 + e];
#pragma unroll
  for (int b = 0; b < NB_; ++b) {
    float sv = sd[(size_t)b * V3 + e];
#pragma unroll
    for (int i = 0; i < VS_G; ++i) acc[i] += beta[(n0 + i) * NB_ + b] * sv;  // uniform -> s_load
  }
#pragma unroll
  for (int i = 0; i < VS_G; ++i) VS[(size_t)(n0 + i) * V3 + e] = acc[i];
}

// ------- Rodrigues: Rs (output) + pose_feature (pfT transposed [k][n]) ------
__global__ void k_rod(const float* __restrict__ theta,
                      float* __restrict__ Rs_out, float* __restrict__ pfT) {
  int i = blockIdx.x * blockDim.x + threadIdx.x;
  if (i >= N_ * J_) return;
  int n = i / J_, j = i % J_;
  const float* th = theta + n * (J_ * 3) + j * 3;
  float t0 = th[0], t1 = th[1], t2 = th[2];
  float angle = sqrtf(t0 * t0 + t1 * t1 + t2 * t2 + 1e-8f);
  float inv = 1.0f / angle;
  float r0 = t0 * inv, r1 = t1 * inv, r2 = t2 * inv;
  float s, c;
  sincosf(angle, &s, &c);
  float omc = 1.0f - c;
  float R[9];
  R[0] = c + omc * r0 * r0;      R[1] = omc * r0 * r1 - s * r2;  R[2] = omc * r0 * r2 + s * r1;
  R[3] = omc * r1 * r0 + s * r2; R[4] = c + omc * r1 * r1;       R[5] = omc * r1 * r2 - s * r0;
  R[6] = omc * r2 * r0 - s * r1; R[7] = omc * r2 * r1 + s * r0;  R[8] = c + omc * r2 * r2;
  float* ro = Rs_out + (size_t)n * (J_ * 9) + j * 9;
#pragma unroll
  for (int k = 0; k < 9; ++k) ro[k] = R[k];
  if (j > 0) {
#pragma unroll
    for (int k = 0; k < 9; ++k)
      pfT[(size_t)((j - 1) * 9 + k) * N_ + n] =
          R[k] - ((k == 0 || k == 4 || k == 8) ? 1.0f : 0.0f);
  }
}

// ---------------- transpose Jr[V][J] -> JrT[J][V] ---------------------------
__global__ __launch_bounds__(256) void k_trans_jr(
    const float* __restrict__ Jr, float* __restrict__ JrT) {
  int idx = blockIdx.x * 256 + threadIdx.x;     // flat over JrT (coalesced writes)
  if (idx >= V_ * J_) return;
  int j = idx / V_, v = idx % V_;
  JrT[idx] = Jr[v * J_ + j];
}

// --------- dst[n,j,c] = sum_v src[n,v,c] * JrT[j,v] -------------------------
#define JRED_NG 2
#define JRED_JG 5
#define JRED_WAVES ((N_ / JRED_NG) * (J_ / JRED_JG))   // 256*7 = 1792
__global__ __launch_bounds__(256) void k_jreduce2(
    const float* __restrict__ src, const float* __restrict__ JrT,
    float* __restrict__ dst) {
  int t = threadIdx.x;
  int lane = t & 63;
  int w = blockIdx.x * 4 + (t >> 6);
  int npair = w / (J_ / JRED_JG);
  int jg    = w % (J_ / JRED_JG);
  int n0 = npair * JRED_NG;
  int j0 = jg * JRED_JG;
  const float* s0 = src + (size_t)n0 * V3;

  float acc[JRED_NG][JRED_JG][3];
#pragma unroll
  for (int nn = 0; nn < JRED_NG; ++nn)
#pragma unroll
    for (int jj = 0; jj < JRED_JG; ++jj)
#pragma unroll
      for (int cc = 0; cc < 3; ++cc) acc[nn][jj][cc] = 0.f;

  for (int iv = 0; iv < (V_ + 63) / 64; ++iv) {
    int v = iv * 64 + lane;
    bool ok = v < V_;
    float jr[JRED_JG];
#pragma unroll
    for (int jj = 0; jj < JRED_JG; ++jj)
      jr[jj] = ok ? JrT[(size_t)(j0 + jj) * V_ + v] : 0.f;
#pragma unroll
    for (int nn = 0; nn < JRED_NG; ++nn) {
      float sx = ok ? s0[(size_t)nn * V3 + 3 * v + 0] : 0.f;
      float sy = ok ? s0[(size_t)nn * V3 + 3 * v + 1] : 0.f;
      float sz = ok ? s0[(size_t)nn * V3 + 3 * v + 2] : 0.f;
#pragma unroll
      for (int jj = 0; jj < JRED_JG; ++jj) {
        acc[nn][jj][0] += jr[jj] * sx;
        acc[nn][jj][1] += jr[jj] * sy;
        acc[nn][jj][2] += jr[jj] * sz;
      }
    }
  }

#pragma unroll
  for (int nn = 0; nn < JRED_NG; ++nn)
#pragma unroll
    for (int jj = 0; jj < JRED_JG; ++jj)
#pragma unroll
      for (int cc = 0; cc < 3; ++cc) {
        float v = acc[nn][jj][cc];
#pragma unroll
        for (int off = 32; off > 0; off >>= 1)
          v += __shfl_down(v, off, 64);
        acc[nn][jj][cc] = v;
      }

  if (lane == 0) {
#pragma unroll
    for (int nn = 0; nn < JRED_NG; ++nn)
#pragma unroll
      for (int jj = 0; jj < JRED_JG; ++jj)
#pragma unroll
        for (int cc = 0; cc < 3; ++cc)
          dst[(n0 + nn) * 105 + (j0 + jj) * 3 + cc] = acc[nn][jj][cc];
  }
}

// ---------------- kinematic chain -> A[n][j][3][4] --------------------------
__global__ __launch_bounds__(256) void k_chain(
    const float* __restrict__ Rs, const float* __restrict__ Jp,
    const float* __restrict__ se, float* __restrict__ Aout) {
  __shared__ float loc[4][J_][12];
  __shared__ float res[4][J_][12];
  int t = threadIdx.x;
  int w = t >> 6, l = t & 63;
  int n = blockIdx.x * 4 + w;

  if (l < J_) {
    int j = l;
    const float* R = Rs + (size_t)n * (J_ * 9) + j * 9;
    float r[9];
#pragma unroll
    for (int k = 0; k < 9; ++k) r[k] = R[k];
    if (j == 0) {
#pragma unroll
      for (int rr = 0; rr < 3; ++rr) {
        loc[w][0][rr * 4 + 0] = r[rr * 3 + 0];
        loc[w][0][rr * 4 + 1] = r[rr * 3 + 1];
        loc[w][0][rr * 4 + 2] = r[rr * 3 + 2];
        loc[w][0][rr * 4 + 3] = Jp[n * 105 + rr];
      }
#pragma unroll
      for (int k = 0; k < 12; ++k) res[w][0][k] = loc[w][0][k];
    } else {
      int p = c_parents[j];
      float si[3], sp[3], jh[3];
#pragma unroll
      for (int cidx = 0; cidx < 3; ++cidx) {
        si[cidx] = se[n * 105 + j * 3 + cidx];
        sp[cidx] = se[n * 105 + p * 3 + cidx];
        jh[cidx] = Jp[n * 105 + j * 3 + cidx] - Jp[n * 105 + p * 3 + cidx];
      }
#pragma unroll
      for (int rr = 0; rr < 3; ++rr) {
        float invp = 1.0f / sp[rr];
        loc[w][j][rr * 4 + 0] = r[rr * 3 + 0] * si[0] * invp;
        loc[w][j][rr * 4 + 1] = r[rr * 3 + 1] * si[1] * invp;
        loc[w][j][rr * 4 + 2] = r[rr * 3 + 2] * si[2] * invp;
        loc[w][j][rr * 4 + 3] = jh[rr];
      }
    }
  }
  __syncthreads();

  for (int i = 1; i < J_; ++i) {
    if (l < 12) {
      int p = c_parents[i];
      int rr = l >> 2, cc = l & 3;
      float acc = (cc == 3) ? res[w][p][rr * 4 + 3] : 0.f;
#pragma unroll
      for (int k = 0; k < 3; ++k)
        acc += res[w][p][rr * 4 + k] * loc[w][i][k * 4 + cc];
      res[w][i][l] = acc;
    }
    __syncthreads();
  }

  if (l < J_) {
    int j = l;
    float jx = Jp[n * 105 + j * 3 + 0];
    float jy = Jp[n * 105 + j * 3 + 1];
    float jz = Jp[n * 105 + j * 3 + 2];
    float* Ao = Aout + (size_t)n * (J_ * 12) + j * 12;
#pragma unroll
    for (int rr = 0; rr < 3; ++rr) {
      float a0 = res[w][j][rr * 4 + 0];
      float a1 = res[w][j][rr * 4 + 1];
      float a2 = res[w][j][rr * 4 + 2];
      float a3 = res[w][j][rr * 4 + 3];
      Ao[rr * 4 + 0] = a0;
      Ao[rr * 4 + 1] = a1;
      Ao[rr * 4 + 2] = a2;
      Ao[rr * 4 + 3] = a3 - (a0 * jx + a1 * jy + a2 * jz);
    }
  }
}

// ----- v_posed = v_shaped + pose_feature @ posedirs (in place, pfT layout) --
// VP_G=32 n's per block; pfT[k][n] so each k reads 32 contiguous floats via
// s_load_dwordx16 x2; pd software-prefetched 1 iter ahead (64 FMA of cover).
#define VP_G 32
__global__ __launch_bounds__(256) void k_vposed2(
    const float* __restrict__ pfT, const float* __restrict__ pd,
    float* __restrict__ VS) {
  int e = blockIdx.x * 256 + threadIdx.x;
  if (e >= V3) return;
  int n0 = blockIdx.y * VP_G;
  float acc[VP_G];
#pragma unroll
  for (int i = 0; i < VP_G; ++i) acc[i] = VS[(size_t)(n0 + i) * V3 + e];
  const float* pdp = pd + e;
  float cur = pdp[0];
  for (int k = 0; k < PF_K - 1; ++k) {
    float nxt = pdp[(size_t)(k + 1) * V3];      // prefetch next pd column
    const float* pk = pfT + (size_t)k * N_ + n0; // uniform, contiguous -> s_load
#pragma unroll
    for (int i = 0; i < VP_G; ++i) acc[i] += pk[i] * cur;
    cur = nxt;
  }
  const float* pk = pfT + (size_t)(PF_K - 1) * N_ + n0;
#pragma unroll
  for (int i = 0; i < VP_G; ++i) acc[i] += pk[i] * cur;
#pragma unroll
  for (int i = 0; i < VP_G; ++i) VS[(size_t)(n0 + i) * V3 + e] = acc[i];
}

// ------ skinning: verts = (sum_j w*A) @ [v_posed,1] + trans (no LDS) --------
// A(n) and trans(n) are block-uniform -> scalar loads (free SGPR operand);
// w row = 35 contiguous floats per thread from L1/L2.
__global__ __launch_bounds__(256) void k_skin2(
    const float* __restrict__ Aw, const float* __restrict__ wts,
    const float* __restrict__ trans, float* __restrict__ VT) {
  int n = blockIdx.y;
  int v = blockIdx.x * 256 + threadIdx.x;
  if (v >= V_) return;
  const float* An = Aw + (size_t)n * (J_ * 12);   // uniform
  const float* wv = wts + (size_t)v * J_;         // 140 contiguous B per lane
  float T[12];
#pragma unroll
  for (int k = 0; k < 12; ++k) T[k] = 0.f;
#pragma unroll
  for (int j = 0; j < J_; ++j) {
    float wj = wv[j];
#pragma unroll
    for (int k = 0; k < 12; ++k) T[k] += wj * An[j * 12 + k];
  }
  float* p = VT + (size_t)n * V3 + 3 * v;
  float x = p[0], y = p[1], z = p[2];
  float tx = trans[n * 3 + 0], ty = trans[n * 3 + 1], tz = trans[n * 3 + 2];
  p[0] = T[0] * x + T[1] * y + T[2]  * z + T[3]  + tx;
  p[1] = T[4] * x + T[5] * y + T[6]  * z + T[7]  + ty;
  p[2] = T[8] * x + T[9] * y + T[10] * z + T[11] + tz;
}

extern "C" void kernel_launch(void* const* d_in, const int* in_sizes, int n_in,
                              void* d_out, int out_size, void* d_ws, size_t ws_size,
                              hipStream_t stream) {
  const float* beta   = (const float*)d_in[0];
  const float* theta  = (const float*)d_in[1];
  const float* se     = (const float*)d_in[2];   // betas_extra (scales)
  const float* deform = (const float*)d_in[3];
  const float* trans  = (const float*)d_in[4];
  const float* vt     = (const float*)d_in[5];
  const float* sd     = (const float*)d_in[6];
  const float* pd     = (const float*)d_in[7];
  const float* Jr     = (const float*)d_in[8];
  const float* wts    = (const float*)d_in[9];

  float* out    = (float*)d_out;
  float* verts  = out;                               // N*V3 (also v_shaped/v_posed buffer)
  float* joints = out + (size_t)N_ * V3;             // N*105
  float* Rs     = joints + (size_t)N_ * 105;         // N*315

  float* ws = (float*)d_ws;
  float* pfT = ws;                                   // PF_K*N = 306*512
  float* Jp  = pfT + (size_t)PF_K * N_;              // N*105
  float* Aw  = Jp + (size_t)N_ * 105;                // N*420
  float* JrT = Aw + (size_t)N_ * 420;                // J*V = 136115

  k_vshaped<<<dim3(46, N_ / VS_G), 256, 0, stream>>>(beta, deform, vt, sd, verts);
  k_trans_jr<<<(V_ * J_ + 255) / 256, 256, 0, stream>>>(Jr, JrT);
  k_rod<<<(N_ * J_ + 63) / 64, 64, 0, stream>>>(theta, Rs, pfT);
  k_jreduce2<<<JRED_WAVES / 4, 256, 0, stream>>>(verts, JrT, Jp);
  k_chain<<<N_ / 4, 256, 0, stream>>>(Rs, Jp, se, Aw);
  k_vposed2<<<dim3(46, N_ / VP_G), 256, 0, stream>>>(pfT, pd, verts);
  k_skin2<<<dim3(16, N_), 256, 0, stream>>>(Aw, wts, trans, verts);
  k_jreduce2<<<JRED_WAVES / 4, 256, 0, stream>>>(verts, JrT, joints);
}